// Round 5
// baseline (195.442 us; speedup 1.0000x reference)
//
#include <hip/hip_runtime.h>
#include <hip/hip_fp16.h>
#include <cstdint>
#include <cstddef>

#define Bb 32
#define Ss 2048
#define Ee 1024
#define Qq 1024
#define Aa 512

typedef _Float16 half8 __attribute__((ext_vector_type(8)));
typedef float f32x4 __attribute__((ext_vector_type(4)));

// ---- workspace byte offsets ----
#define WS_PROJQ 0u          // 32*512 f32      = 65536 B
#define WS_MPART 65536u      // 32*64 f32       = 8192 B
#define WS_LPART 73728u      // 32*64 f32       = 8192 B
#define WS_CTXP  81920u      // 32*64*512 f32   = 4194304 B
#define WS_WWS   4276224u    // 1024*512 f16    = 1048576 B   (total ~5.1 MB)

__device__ __forceinline__ float fast_tanh(float x) {
  float e = __expf(2.0f * x);
  return 1.0f - __fdividef(2.0f, e + 1.0f);
}

// ---- W_in fp32 [E][A] -> fp16 tiled [kt][ks][a][8]  (1 MB, L2-resident)
__global__ void k_convw(const float* __restrict__ win, _Float16* __restrict__ wws) {
  int gid = blockIdx.x * 256 + threadIdx.x;
  int a  = gid & 511;
  int ks = (gid >> 9) & 3;
  int kt = gid >> 11;
  int k0 = kt * 32 + ks * 8;
  half8 v;
  #pragma unroll
  for (int j = 0; j < 8; ++j) v[j] = (_Float16)win[(size_t)(k0 + j) * Aa + a];
  *(half8*)(wws + ((size_t)kt * 16384 + (size_t)ks * 4096 + (size_t)a * 8)) = v;
}

// ---- proj_q[b][a]
__global__ void k_projq(const float* __restrict__ query, const float* __restrict__ wq,
                        float* __restrict__ projq) {
  __shared__ float red[256];
  int b  = blockIdx.y;
  int al = threadIdx.x & 63;
  int eq = threadIdx.x >> 6;
  int a  = blockIdx.x * 64 + al;
  const float* q = query + (size_t)b * Qq;
  float s = 0.f;
  int e0 = eq * 256;
  #pragma unroll 4
  for (int e = e0; e < e0 + 256; ++e)
    s += q[e] * wq[(size_t)e * Aa + a];
  red[threadIdx.x] = s;
  __syncthreads();
  if (eq == 0)
    projq[(size_t)b * Aa + a] = red[al] + red[al + 64] + red[al + 128] + red[al + 192];
}

// ---- main: 32-row s-chunk x 512 cols, 256 threads (wave w owns cols w*128..+127)
// acc[2][8] = 64 f32/thread -> ~110 total regs -> 4 blocks/CU resident.
// A: f16 LDS double-buffer (4 KB), staged by threads 0..127 ONLY (exact tile coverage).
// B: direct per-lane 16B loads from L2-resident tiled wws.
__global__ __launch_bounds__(256, 4)
void k_main(const float* __restrict__ inp, const _Float16* __restrict__ wws,
            const float* __restrict__ projq, const float* __restrict__ watt,
            float* __restrict__ mpart, float* __restrict__ lpart,
            float* __restrict__ ctxp)
{
  __shared__ __align__(16) _Float16 Alds[2][4 * 32 * 8];   // [p][kb][row32][8]  2x2KB
  __shared__ float pq_s[512];
  __shared__ float wa_s[512];
  __shared__ float sc4[32][4];
  __shared__ float pbuf[32];

  const int tid = threadIdx.x;
  const int l   = tid & 63;
  const int w   = tid >> 6;        // wave = col-slice 0..3
  const int lr  = l & 15;
  const int kb  = l >> 4;          // k-slot 0..3 (frag k-group)
  const int b   = blockIdx.y;
  const int ch  = blockIdx.x;      // s-chunk of 32 rows, 0..63

  pq_s[tid]       = projq[(size_t)b * Aa + tid];
  pq_s[tid + 256] = projq[(size_t)b * Aa + tid + 256];
  wa_s[tid]       = watt[tid];
  wa_s[tid + 256] = watt[tid + 256];

  // A staging: threads 0..127 own (kbs = (tid>>5)&3, rows = tid&31), 8 f32 per K-step.
  // 128 threads x 8 halfs = 1024 halfs = exactly the 32x32 f16 tile.
  const bool astage = (tid < 128);
  const int kbs  = (tid >> 5) & 3;
  const int rows = tid & 31;
  const float* asrc = inp + ((size_t)(b * Ss + ch * 32 + rows)) * Ee + kbs * 8;
  const int aoff = (kbs * 32 + rows) * 8;        // f16 element offset

  // B fragment base (R2-verified): wws half8-index = kt*2048 + kb*512 + col
  const half8* Bg = (const half8*)wws + (size_t)kb * 512 + w * 128 + lr;

  f32x4 acc[2][8];
  #pragma unroll
  for (int m = 0; m < 2; ++m)
    #pragma unroll
    for (int n = 0; n < 8; ++n) acc[m][n] = (f32x4){0.f, 0.f, 0.f, 0.f};

  // ---- prologue: stage A for kt=0 into buffer 0
  if (astage) {
    float4 f0 = *(const float4*)(asrc);
    float4 f1 = *(const float4*)(asrc + 4);
    half8 h;
    h[0]=(_Float16)f0.x; h[1]=(_Float16)f0.y; h[2]=(_Float16)f0.z; h[3]=(_Float16)f0.w;
    h[4]=(_Float16)f1.x; h[5]=(_Float16)f1.y; h[6]=(_Float16)f1.z; h[7]=(_Float16)f1.w;
    *(half8*)(Alds[0] + aoff) = h;
  }
  __syncthreads();

  int p = 0;
  for (int kt = 0; kt < 32; ++kt) {
    // 1) A prefetch for kt+1 (HBM latency hidden under MFMAs); waves 0..1 only
    float4 f0, f1;
    if (astage) {
      const int ktn = (kt < 31) ? kt + 1 : 31;
      const float* ap = asrc + (size_t)ktn * 32;
      f0 = *(const float4*)(ap);
      f1 = *(const float4*)(ap + 4);
    }

    // 2) B first half (L2)
    const half8* Bk = Bg + (size_t)kt * 2048;
    half8 bf0 = Bk[0], bf1 = Bk[16], bf2 = Bk[32], bf3 = Bk[48];

    // 3) A fragments from LDS[p]
    half8 af0 = *(const half8*)(Alds[p] + (kb * 32 +      lr) * 8);
    half8 af1 = *(const half8*)(Alds[p] + (kb * 32 + 16 + lr) * 8);

    // 4) MFMA group 1 (n=0..3)
    acc[0][0] = __builtin_amdgcn_mfma_f32_16x16x32_f16(af0, bf0, acc[0][0], 0, 0, 0);
    acc[1][0] = __builtin_amdgcn_mfma_f32_16x16x32_f16(af1, bf0, acc[1][0], 0, 0, 0);
    acc[0][1] = __builtin_amdgcn_mfma_f32_16x16x32_f16(af0, bf1, acc[0][1], 0, 0, 0);
    acc[1][1] = __builtin_amdgcn_mfma_f32_16x16x32_f16(af1, bf1, acc[1][1], 0, 0, 0);
    acc[0][2] = __builtin_amdgcn_mfma_f32_16x16x32_f16(af0, bf2, acc[0][2], 0, 0, 0);
    acc[1][2] = __builtin_amdgcn_mfma_f32_16x16x32_f16(af1, bf2, acc[1][2], 0, 0, 0);
    acc[0][3] = __builtin_amdgcn_mfma_f32_16x16x32_f16(af0, bf3, acc[0][3], 0, 0, 0);
    acc[1][3] = __builtin_amdgcn_mfma_f32_16x16x32_f16(af1, bf3, acc[1][3], 0, 0, 0);

    // 5) B second half + MFMA group 2
    half8 bf4 = Bk[64], bf5 = Bk[80], bf6 = Bk[96], bf7 = Bk[112];
    acc[0][4] = __builtin_amdgcn_mfma_f32_16x16x32_f16(af0, bf4, acc[0][4], 0, 0, 0);
    acc[1][4] = __builtin_amdgcn_mfma_f32_16x16x32_f16(af1, bf4, acc[1][4], 0, 0, 0);
    acc[0][5] = __builtin_amdgcn_mfma_f32_16x16x32_f16(af0, bf5, acc[0][5], 0, 0, 0);
    acc[1][5] = __builtin_amdgcn_mfma_f32_16x16x32_f16(af1, bf5, acc[1][5], 0, 0, 0);
    acc[0][6] = __builtin_amdgcn_mfma_f32_16x16x32_f16(af0, bf6, acc[0][6], 0, 0, 0);
    acc[1][6] = __builtin_amdgcn_mfma_f32_16x16x32_f16(af1, bf6, acc[1][6], 0, 0, 0);
    acc[0][7] = __builtin_amdgcn_mfma_f32_16x16x32_f16(af0, bf7, acc[0][7], 0, 0, 0);
    acc[1][7] = __builtin_amdgcn_mfma_f32_16x16x32_f16(af1, bf7, acc[1][7], 0, 0, 0);

    // 6) stage A kt+1 into other buffer
    if (astage && kt < 31) {
      half8 h;
      h[0]=(_Float16)f0.x; h[1]=(_Float16)f0.y; h[2]=(_Float16)f0.z; h[3]=(_Float16)f0.w;
      h[4]=(_Float16)f1.x; h[5]=(_Float16)f1.y; h[6]=(_Float16)f1.z; h[7]=(_Float16)f1.w;
      *(half8*)(Alds[p ^ 1] + aoff) = h;
    }
    __syncthreads();
    p ^= 1;
  }

  // ---------------- epilogue ----------------
  // C/D: col = lane&15, row(frag) = kb*4 + j ; global row = m*16 + kb*4 + j
  float sp[2][4];
  #pragma unroll
  for (int m = 0; m < 2; ++m)
    #pragma unroll
    for (int j = 0; j < 4; ++j) sp[m][j] = 0.f;

  #pragma unroll
  for (int n = 0; n < 8; ++n) {
    int col = w * 128 + n * 16 + lr;
    float wan = wa_s[col], pqn = pq_s[col];
    #pragma unroll
    for (int m = 0; m < 2; ++m)
      #pragma unroll
      for (int j = 0; j < 4; ++j)
        sp[m][j] += fast_tanh(acc[m][n][j] + pqn) * wan;
  }
  #pragma unroll
  for (int m = 0; m < 2; ++m)
    #pragma unroll
    for (int j = 0; j < 4; ++j) {
      float v = sp[m][j];
      v += __shfl_xor(v, 1);
      v += __shfl_xor(v, 2);
      v += __shfl_xor(v, 4);
      v += __shfl_xor(v, 8);
      sp[m][j] = v;                      // reduced over this wave's 16-col group
    }
  if (lr == 0) {
    #pragma unroll
    for (int m = 0; m < 2; ++m)
      #pragma unroll
      for (int j = 0; j < 4; ++j)
        sc4[m * 16 + kb * 4 + j][w] = sp[m][j];
  }
  __syncthreads();

  const int pi = b * 64 + ch;
  if (tid < 32) {
    float s = sc4[tid][0] + sc4[tid][1] + sc4[tid][2] + sc4[tid][3];
    float mx = s;
    #pragma unroll
    for (int off = 1; off < 32; off <<= 1) mx = fmaxf(mx, __shfl_xor(mx, off));
    float pe = __expf(s - mx);
    float ls = pe;
    #pragma unroll
    for (int off = 1; off < 32; off <<= 1) ls += __shfl_xor(ls, off);
    pbuf[tid] = pe;
    if (tid == 0) { mpart[pi] = mx; lpart[pi] = ls; }
  }
  __syncthreads();

  // ctx partial: sum_s p[s] * proj[s][col]
  float cv[8];
  #pragma unroll
  for (int n = 0; n < 8; ++n) cv[n] = 0.f;
  #pragma unroll
  for (int m = 0; m < 2; ++m)
    #pragma unroll
    for (int j = 0; j < 4; ++j) {
      float pw = pbuf[m * 16 + kb * 4 + j];
      #pragma unroll
      for (int n = 0; n < 8; ++n) cv[n] += pw * acc[m][n][j];
    }
  #pragma unroll
  for (int n = 0; n < 8; ++n) {
    float v = cv[n];
    v += __shfl_xor(v, 16);
    v += __shfl_xor(v, 32);
    cv[n] = v;                           // sum over all 32 rows
  }
  if (l < 16) {
    #pragma unroll
    for (int n = 0; n < 8; ++n)
      ctxp[(size_t)pi * 512 + w * 128 + n * 16 + l] = cv[n];
  }
}

// ---- merge 64 chunk partials per batch (flash-style combine)
__global__ void k_comb(const float* __restrict__ mpart, const float* __restrict__ lpart,
                       const float* __restrict__ ctxp, float* __restrict__ out) {
  int b = blockIdx.x, a = threadIdx.x;
  float Mg = -1e30f;
  #pragma unroll 8
  for (int i = 0; i < 64; ++i) Mg = fmaxf(Mg, mpart[b * 64 + i]);
  float den = 0.f, s = 0.f;
  #pragma unroll 8
  for (int i = 0; i < 64; ++i) {
    float e = __expf(mpart[b * 64 + i] - Mg);
    den += lpart[b * 64 + i] * e;
    s   += ctxp[((size_t)(b * 64 + i)) * 512 + a] * e;
  }
  out[(size_t)b * 512 + a] = s / den;
}

extern "C" void kernel_launch(void* const* d_in, const int* in_sizes, int n_in,
                              void* d_out, int out_size, void* d_ws, size_t ws_size,
                              hipStream_t stream) {
  const float* inputs = (const float*)d_in[0];
  const float* query  = (const float*)d_in[1];
  const float* W_in   = (const float*)d_in[2];
  const float* W_q    = (const float*)d_in[3];
  const float* w_att  = (const float*)d_in[4];
  float* out = (float*)d_out;

  char* ws = (char*)d_ws;
  float*    projq = (float*)(ws + WS_PROJQ);
  float*    mpart = (float*)(ws + WS_MPART);
  float*    lpart = (float*)(ws + WS_LPART);
  float*    ctxp  = (float*)(ws + WS_CTXP);
  _Float16* wws   = (_Float16*)(ws + WS_WWS);

  k_convw<<<256, 256, 0, stream>>>(W_in, wws);
  k_projq<<<dim3(8, 32), 256, 0, stream>>>(query, W_q, projq);
  k_main<<<dim3(64, 32), 256, 0, stream>>>(inputs, wws, projq, w_att, mpart, lpart, ctxp);
  k_comb<<<32, 512, 0, stream>>>(mpart, lpart, ctxp, out);
}